// Round 10
// baseline (29.446 us; speedup 1.0000x reference)
//
#include <hip/hip_runtime.h>
#include <math.h>

// RoI max pooling: feats (1,256,128,128) f32, rois (1,256,4) int32 {x,y,w,h},
// out (N=256, C=256, 7, 7) f32.  One wave per (n, channel PAIR).
//
// R9 structure (exec-masked batched loads) + 2 channels/wave:
//   q = lane&7 (column quad), b = lane>>3 (row bin, b==7 masked).
//   Per slot-group: 8 row loads x 2 channels batched into ONE in-flight
//   group (16 loads, 64 dest VGPRs), masked by (b<7)&&(quad<wa)&&(dr<nr_b);
//   masked lanes issue no L1 requests. dr literal -> offset immediates.
//   Slot1 (cols 4q) then slot2 (cols 32+4q, only when wa>32): writes of
//   slot1 retire before slot2 consumes -> peak regs capped.
//   Channels share ALL geometry -> setup VALU, roi fetch, fence, and
//   read-phase index math amortize over 2 channels; wave count halves
//   (R7's same idea regressed because its loads were a serialized branchy
//   chain -- doubling serial latency; here exposure count is unchanged).
//
// Read phase: lane l=i*7+j IS the output offset; per ch reads
// lds[ch][i][pad+sxr..+7], masks t<wj, 7 maxes, contiguous 196B store.
// Same-wave DS in-order -> lgkmcnt(0) fence, no barrier.

constexpr int kC = 256, kH = 128, kW = 128, kN = 256, kOut = 7;
constexpr int kStr = 68;  // dwords/bin-row: 16B-aligned

__device__ __forceinline__ float4 fmax4(float4 a, const float4 b) {
  a.x = fmaxf(a.x, b.x); a.y = fmaxf(a.y, b.y);
  a.z = fmaxf(a.z, b.z); a.w = fmaxf(a.w, b.w);
  return a;
}

__device__ __forceinline__ void slot_pair(
    const float* __restrict__ p0, const float* __restrict__ p1,
    const int nr, const int nrb, const int cofs, const bool msk,
    const int bin, float* __restrict__ w0, float* __restrict__ w1) {
  const float4 kNeg = make_float4(-INFINITY, -INFINITY, -INFINITY, -INFINITY);
  float4 u[8], v[8];
#pragma unroll
  for (int dr = 0; dr < 8; ++dr) {
    u[dr] = kNeg; v[dr] = kNeg;
    if (dr < nrb) {                       // wave-uniform row skip
      if (msk && dr < nr) {
        u[dr] = *(const float4*)(p0 + dr * kW + cofs);
        v[dr] = *(const float4*)(p1 + dr * kW + cofs);
      }
    }
  }
  const float4 r0 = fmax4(fmax4(fmax4(u[0], u[1]), fmax4(u[2], u[3])),
                          fmax4(fmax4(u[4], u[5]), fmax4(u[6], u[7])));
  const float4 r1 = fmax4(fmax4(fmax4(v[0], v[1]), fmax4(v[2], v[3])),
                          fmax4(fmax4(v[4], v[5]), fmax4(v[6], v[7])));
  if (msk) {
    *(float4*)(w0 + bin * kStr + cofs) = r0;
    *(float4*)(w1 + bin * kStr + cofs) = r1;
  }
}

__global__ __launch_bounds__(256, 4) void roipool_kernel(
    const float* __restrict__ feats,
    const int* __restrict__ rois,
    float* __restrict__ out) {
  __shared__ float lds[4][2][7 * kStr];  // 15232 B

  const int lane = threadIdx.x & 63;
  const int wid  = __builtin_amdgcn_readfirstlane(threadIdx.x) >> 6;
  const int bid  = blockIdx.x;

  // XCD-affine mapping (perf heuristic): xcd = bid & 7, n-fastest per cgrp
  const int xcd  = bid & 7;
  const int idx  = bid >> 3;
  const int n    = idx & (kN - 1);
  const int cgrp = ((idx >> 8) << 3) | xcd;    // 0..31
  const int c0   = (cgrp << 3) | (wid << 1);   // 8 ch/block, 2 per wave

  const int4 roi = ((const int4*)rois)[n];
  const int x = __builtin_amdgcn_readfirstlane(roi.x);
  const int y = __builtin_amdgcn_readfirstlane(roi.y);
  const int w = __builtin_amdgcn_readfirstlane(roi.z);
  const int h = __builtin_amdgcn_readfirstlane(roi.w);

  const int xa  = x & ~3;
  const int pad = x - xa;
  const int wa  = pad + w;          // <= 59

  const int q  = lane & 7;          // column-quad slot
  const int b  = lane >> 3;         // row-bin slot; b==7 fully masked
  const int bc = (b < 7) ? b : 6;

  // per-lane bin row bounds (magic-div by 7)
  const int bh   = bc * h;
  const int s_b  = bh / 7;
  int nr         = (bh + h + 6) / 7 - s_b;
  if (nr > 8) nr = 8;               // MAX_BIN clamp
  const int sy_b = y + s_b;

  int nrb = (h + 12) / 7;           // uniform: nrb >= every bin's nr
  if (nrb > 8) nrb = 8;

  const int c1 = 4 * q;
  const int c2 = 32 + 4 * q;
  const bool m1 = (b < 7) && (c1 < wa);
  const bool m2 = (b < 7) && (c2 < wa);

  const float* __restrict__ p0 =
      feats + (((unsigned)c0 << 14) + ((unsigned)sy_b << 7) + (unsigned)xa);
  const float* __restrict__ p1 = p0 + (1u << 14);

  float* __restrict__ w0 = lds[wid][0];
  float* __restrict__ w1 = lds[wid][1];

  slot_pair(p0, p1, nr, nrb, c1, m1, bc, w0, w1);
  if (wa > 32) slot_pair(p0, p1, nr, nrb, c2, m2, bc, w0, w1);

  // drain LDS writes before cross-lane reads (same-wave, no barrier)
  asm volatile("s_waitcnt lgkmcnt(0)" ::: "memory");

  // read phase: lane l = i*7 + j -> output offset directly (shared geometry)
  const int l49 = (lane < 49) ? lane : 48;
  const int i   = (l49 * 37) >> 8;                 // floor(l49/7)
  const int j   = l49 - i * 7;
  const int jw  = j * w;
  const int sxr = (jw * 9363) >> 16;               // floor(jw/7)
  const int exr = ((jw + w + 6) * 9363) >> 16;     // floor(((j+1)w+6)/7)
  int wj = exr - sxr;
  if (wj > 8) wj = 8;                              // MAX_BIN clamp
  const int robs = i * kStr + pad + sxr;

#pragma unroll
  for (int ch = 0; ch < 2; ++ch) {
    const float* __restrict__ rbase = lds[wid][ch] + robs;
    float acc = rbase[0];                          // t=0 always valid
#pragma unroll
    for (int t = 1; t < 8; ++t) {
      const float v = rbase[t];
      acc = fmaxf(acc, (t < wj) ? v : -INFINITY);  // cndmask discards junk
    }
    if (lane < 49)
      out[((size_t)n * kC + (c0 + ch)) * 49 + lane] = acc;
  }
}

extern "C" void kernel_launch(void* const* d_in, const int* in_sizes, int n_in,
                              void* d_out, int out_size, void* d_ws, size_t ws_size,
                              hipStream_t stream) {
  const float* feats = (const float*)d_in[0];
  const int*   rois  = (const int*)d_in[1];
  float*       out   = (float*)d_out;
  dim3 grid((kC / 8) * kN);   // 8192 blocks: 8 channels/block, 2 per wave
  dim3 block(256);
  roipool_kernel<<<grid, block, 0, stream>>>(feats, rois, out);
}

// Round 11
// 27.645 us; speedup vs baseline: 1.0652x; 1.0652x over previous
//
#include <hip/hip_runtime.h>
#include <math.h>

// RoI max pooling: feats (1,256,128,128) f32, rois (1,256,4) int32 {x,y,w,h},
// out (N=256, C=256, 7, 7) f32.  One wave per (n, c).
//
// R9 structure (exec-masked batched loads) + occupancy push:
//   q = lane&7 (column quad), b = lane>>3 (row bin, b==7 masked).
//   Per quad-slot: 8 row loads into v[8] (init -INF), masked by
//   (b<7)&&(quad<wa)&&(dr<nr_b) -- masked lanes issue no L1 traffic;
//   dr literal -> shared base + offset immediates. ONE slot's loads live
//   at a time (32 dest VGPRs peak) so the kernel fits 64 VGPRs ->
//   __launch_bounds__(256, 8) -> 8 waves/SIMD (was ~5 with both slots
//   live). Kernel is latency-exposure bound (R7/R10: per-wave work
//   scaling fails; R8: straight-line load batching fails; R9: byte cut
//   gave only ~2us) -> more resident waves is the remaining lever.
//   Slot2 (cols 32+4q) skipped wave-uniformly when wa<=32 (~50% of rois);
//   rows skipped uniformly at dr>=nrb (nrb >= every bin's nr).
//
// Read phase: lane l=i*7+j IS the output offset; reads lds[i][pad+sxr..+7],
// masks t<wj (MAX_BIN clamp), 7 maxes, one contiguous 196B store.
// Same-wave DS ordering is in-order -> lgkmcnt(0) fence, no barrier.

constexpr int kC = 256, kH = 128, kW = 128, kN = 256, kOut = 7;
constexpr int kStr = 68;  // dwords/bin-row: 16B-aligned

__device__ __forceinline__ float4 fmax4(float4 a, const float4 b) {
  a.x = fmaxf(a.x, b.x); a.y = fmaxf(a.y, b.y);
  a.z = fmaxf(a.z, b.z); a.w = fmaxf(a.w, b.w);
  return a;
}

__device__ __forceinline__ void do_slot(
    const float* __restrict__ prow, const int nr, const int nrb,
    const int cofs, const bool msk, const int bin, float* __restrict__ wl) {
  const float4 kNeg = make_float4(-INFINITY, -INFINITY, -INFINITY, -INFINITY);
  float4 v[8];
#pragma unroll
  for (int dr = 0; dr < 8; ++dr) {
    v[dr] = kNeg;
    if (dr < nrb) {                        // wave-uniform row skip
      if (msk && dr < nr)                  // exec mask: no L1 traffic if off
        v[dr] = *(const float4*)(prow + dr * kW + cofs);
    }
  }
  const float4 r = fmax4(fmax4(fmax4(v[0], v[1]), fmax4(v[2], v[3])),
                         fmax4(fmax4(v[4], v[5]), fmax4(v[6], v[7])));
  if (msk) *(float4*)(wl + bin * kStr + cofs) = r;
}

__global__ __launch_bounds__(256, 8) void roipool_kernel(
    const float* __restrict__ feats,
    const int* __restrict__ rois,
    float* __restrict__ out) {
  __shared__ float lds[4][7 * kStr];  // 7616 B (not occupancy-limiting)

  const int lane = threadIdx.x & 63;
  const int wid  = __builtin_amdgcn_readfirstlane(threadIdx.x) >> 6;
  const int bid  = blockIdx.x;

  // XCD-affine mapping (perf heuristic): xcd = bid & 7, n-fastest per cg
  const int xcd = bid & 7;
  const int idx = bid >> 3;
  const int n   = idx & (kN - 1);
  const int cg  = ((idx >> 8) << 3) | xcd;
  const int c   = (cg << 2) | wid;

  const int4 roi = ((const int4*)rois)[n];   // n uniform -> scalar path
  const int x = __builtin_amdgcn_readfirstlane(roi.x);
  const int y = __builtin_amdgcn_readfirstlane(roi.y);
  const int w = __builtin_amdgcn_readfirstlane(roi.z);
  const int h = __builtin_amdgcn_readfirstlane(roi.w);

  const int xa  = x & ~3;
  const int pad = x - xa;
  const int wa  = pad + w;          // <= 59

  const int q  = lane & 7;          // column-quad slot
  const int b  = lane >> 3;         // row-bin slot; b==7 fully masked
  const int bc = (b < 7) ? b : 6;

  // per-lane bin row bounds (magic-div by 7)
  const int bh   = bc * h;
  const int s_b  = bh / 7;
  int nr         = (bh + h + 6) / 7 - s_b;
  if (nr > 8) nr = 8;               // MAX_BIN clamp
  const int sy_b = y + s_b;

  int nrb = (h + 12) / 7;           // uniform: nrb >= every bin's nr
  if (nrb > 8) nrb = 8;

  const int c1 = 4 * q;
  const int c2 = 32 + 4 * q;
  const bool m1 = (b < 7) && (c1 < wa);
  const bool m2 = (b < 7) && (c2 < wa);

  const float* __restrict__ prow =
      feats + (((unsigned)c << 14) + ((unsigned)sy_b << 7) + (unsigned)xa);

  float* __restrict__ wl = lds[wid];
  do_slot(prow, nr, nrb, c1, m1, bc, wl);
  if (wa > 32) do_slot(prow, nr, nrb, c2, m2, bc, wl);

  // drain LDS writes before cross-lane reads (same-wave, no barrier)
  asm volatile("s_waitcnt lgkmcnt(0)" ::: "memory");

  // read phase: lane l = i*7 + j -> output offset directly
  const int l49 = (lane < 49) ? lane : 48;
  const int i   = (l49 * 37) >> 8;                 // floor(l49/7)
  const int j   = l49 - i * 7;
  const int jw  = j * w;
  const int sxr = (jw * 9363) >> 16;               // floor(jw/7)
  const int exr = ((jw + w + 6) * 9363) >> 16;     // floor(((j+1)w+6)/7)
  int wj = exr - sxr;
  if (wj > 8) wj = 8;                              // MAX_BIN clamp

  const float* __restrict__ rbase = wl + i * kStr + pad + sxr;
  float acc = rbase[0];                            // t=0 always valid
#pragma unroll
  for (int t = 1; t < 8; ++t) {
    const float v = rbase[t];
    acc = fmaxf(acc, (t < wj) ? v : -INFINITY);    // cndmask discards junk
  }

  if (lane < 49)
    out[((size_t)n * kC + c) * 49 + lane] = acc;
}

extern "C" void kernel_launch(void* const* d_in, const int* in_sizes, int n_in,
                              void* d_out, int out_size, void* d_ws, size_t ws_size,
                              hipStream_t stream) {
  const float* feats = (const float*)d_in[0];
  const int*   rois  = (const int*)d_in[1];
  float*       out   = (float*)d_out;
  dim3 grid((kC / 4) * kN);
  dim3 block(256);
  roipool_kernel<<<grid, block, 0, stream>>>(feats, rois, out);
}